// Round 7
// baseline (181.734 us; speedup 1.0000x reference)
//
#include <hip/hip_runtime.h>

typedef __attribute__((ext_vector_type(8))) _Float16 half8;
typedef __attribute__((ext_vector_type(4))) float floatx4;

constexpr int NB  = 2;
constexpr int CC  = 64;
constexpr int DD  = 16;
constexpr int HH  = 32;
constexpr int WW  = 32;
constexpr int KN_ = 27;
constexpr int OC  = 64;
constexpr int DHW = DD * HH * WW;   // 16384
constexpr int TP  = 16;             // positions per wave-tile

__device__ __forceinline__ unsigned short f2h(float f) {
    _Float16 h = (_Float16)f;
    return *(unsigned short*)&h;
}

// ---------------------------------------------------------------------------
// Prep kernel (merged):
//  blocks [0, 512)   : NCDHW f32 -> NDHWC f16  (64 ch contiguous per voxel)
//  blocks [512, 944) : weight (o,c,k) f32 -> f16 MFMA A-fragment stream
//    wf[(((k*2+cc)*4+ot)*64 + l)*8 + i] = W[o=ot*16+(l&15)][c=cc*32+(l>>4)*8+i][k]
__global__ __launch_bounds__(256) void k_prep(const float* __restrict__ in,
                                              const float* __restrict__ w,
                                              unsigned int* __restrict__ outu,
                                              unsigned short* __restrict__ wf) {
    int bid = blockIdx.x;
    int t = threadIdx.x;
    if (bid < 512) {
        __shared__ float tile[64][65];
        int n  = bid >> 8;
        int v0 = (bid & 255) << 6;
        int lane = t & 63, row = t >> 6;
#pragma unroll
        for (int i = 0; i < 16; ++i) {
            int c = (i << 2) + row;
            tile[c][lane] = in[(size_t)(n * CC + c) * DHW + v0 + lane];
        }
        __syncthreads();
#pragma unroll
        for (int i = 0; i < 8; ++i) {
            int flat = i * 256 + t;
            int v = flat >> 5, cd = flat & 31;
            unsigned int lo = f2h(tile[2 * cd][v]);
            unsigned int hi = f2h(tile[2 * cd + 1][v]);
            outu[(size_t)(n * DHW + v0 + v) * 32 + cd] = lo | (hi << 16);
        }
    } else {
        int f = (bid - 512) * 256 + t;   // 110592 total
        int i  = f & 7;
        int l  = (f >> 3) & 63;
        int ot = (f >> 9) & 3;
        int cc = (f >> 11) & 1;
        int k  = f >> 12;
        int o = ot * 16 + (l & 15);
        int c = cc * 32 + ((l >> 4) << 3) + i;
        wf[f] = f2h(w[(o * CC + c) * KN_ + k]);
    }
}

// ---------------------------------------------------------------------------
// Barrier-free wave-private deformable conv.
// 64-thread blocks (1 wave). Wave = 16 positions x all 64 outputs x 27 taps.
// Lane l: position p = l&15, channel chunks (l>>4)*8 and 32+(l>>4)*8.
// The two interp accumulators ARE the MFMA B-fragments -> no S staging at all.
__global__ __launch_bounds__(64, 2) void k_main(const unsigned short* __restrict__ inp,
                                                const unsigned short* __restrict__ wf,
                                                const float* __restrict__ offs,
                                                float* __restrict__ out) {
    __shared__ uint4 SUV[KN_ * TP];   // 432 recs: 8 x u16 voxel ids      (6.9KB)
    __shared__ uint4 SUW[KN_ * TP];   // 432 recs: 8 x f16 corner weights (6.9KB)

    int l   = threadIdx.x;
    int bid = blockIdx.x;
    int n   = (bid >> 2) & 1;                      // XCDs 0-3 -> n=0, 4-7 -> n=1
    int idx = ((bid >> 3) << 2) | (bid & 3);       // 0..1023
    int p0  = idx << 4;

    const float* offb = offs + (size_t)n * (3 * KN_) * DHW + p0;
    const char*  inb  = (const char*)(inp + ((size_t)n * DHW << 6));

    // ---- setup: 432 (k,p) sampling records, coordinate math once each ----
    for (int si = l; si < KN_ * TP; si += 64) {
        int k = si >> 4, p = si & 15;
        int pa = p0 + p;
        int dpos = pa >> 10, hpos = (pa >> 5) & 31, wpos = pa & 31;

        float oz = offb[(k * 3 + 0) * DHW + p];
        float oy = offb[(k * 3 + 1) * DHW + p];
        float ox = offb[(k * 3 + 2) * DHW + p];
        float ix = ((float)wpos + ox) * (32.0f / 31.0f) - 0.5f;
        float iy = ((float)hpos + oy) * (32.0f / 31.0f) - 0.5f;
        float iz = ((float)dpos + oz) * (16.0f / 15.0f) - 0.5f;
        float xf = floorf(ix), yf = floorf(iy), zf = floorf(iz);
        float fx = ix - xf, fy = iy - yf, fz = iz - zf;
        int x0 = (int)xf, y0 = (int)yf, z0 = (int)zf;

        float wx0 = ((unsigned)x0       < (unsigned)WW) ? 1.f - fx : 0.f;
        float wx1 = ((unsigned)(x0 + 1) < (unsigned)WW) ? fx       : 0.f;
        float wy0 = ((unsigned)y0       < (unsigned)HH) ? 1.f - fy : 0.f;
        float wy1 = ((unsigned)(y0 + 1) < (unsigned)HH) ? fy       : 0.f;
        float wz0 = ((unsigned)z0       < (unsigned)DD) ? 1.f - fz : 0.f;
        float wz1 = ((unsigned)(z0 + 1) < (unsigned)DD) ? fz       : 0.f;

        int xc0 = min(max(x0, 0), WW - 1), xc1 = min(max(x0 + 1, 0), WW - 1);
        int yc0 = min(max(y0, 0), HH - 1), yc1 = min(max(y0 + 1, 0), HH - 1);
        int zc0 = min(max(z0, 0), DD - 1), zc1 = min(max(z0 + 1, 0), DD - 1);

        float wzy00 = wz0 * wy0, wzy01 = wz0 * wy1, wzy10 = wz1 * wy0, wzy11 = wz1 * wy1;
        unsigned int b00 = (zc0 * HH + yc0) * WW, b01 = (zc0 * HH + yc1) * WW;
        unsigned int b10 = (zc1 * HH + yc0) * WW, b11 = (zc1 * HH + yc1) * WW;

        uint4 vp, wp;
        vp.x = (b00 + xc0) | ((b00 + xc1) << 16);
        vp.y = (b01 + xc0) | ((b01 + xc1) << 16);
        vp.z = (b10 + xc0) | ((b10 + xc1) << 16);
        vp.w = (b11 + xc0) | ((b11 + xc1) << 16);
        wp.x = (unsigned int)f2h(wzy00 * wx0) | ((unsigned int)f2h(wzy00 * wx1) << 16);
        wp.y = (unsigned int)f2h(wzy01 * wx0) | ((unsigned int)f2h(wzy01 * wx1) << 16);
        wp.z = (unsigned int)f2h(wzy10 * wx0) | ((unsigned int)f2h(wzy10 * wx1) << 16);
        wp.w = (unsigned int)f2h(wzy11 * wx0) | ((unsigned int)f2h(wzy11 * wx1) << 16);

        SUV[si] = vp;
        SUW[si] = wp;
    }
    __syncthreads();   // single wave: compiles to a waitcnt, negligible

    const int prow = l & 15;          // position in tile == MFMA col
    const int cp   = l >> 4;          // channel chunk pair: cp and cp+4
    const int cpo  = cp << 4;         // byte offset of chunk cp in 128B voxel row

    floatx4 acc0 = {0.f, 0.f, 0.f, 0.f};
    floatx4 acc1 = {0.f, 0.f, 0.f, 0.f};
    floatx4 acc2 = {0.f, 0.f, 0.f, 0.f};
    floatx4 acc3 = {0.f, 0.f, 0.f, 0.f};

    for (int k = 0; k < KN_; ++k) {
        // sampling record (broadcast across the 4 lanes sharing a position)
        const uint4 vp = SUV[(k << 4) + prow];
        const uint4 wp = SUW[(k << 4) + prow];
        const unsigned int vpa[4] = {vp.x, vp.y, vp.z, vp.w};
        const unsigned int wpa[4] = {wp.x, wp.y, wp.z, wp.w};

        // A fragments for this tap (8 x 16B, L2-resident stream)
        const unsigned short* wfk = wf + ((size_t)(k << 3) << 9) + (l << 3);
        half8 wa0 = *(const half8*)(wfk);            // cc=0, ot=0
        half8 wa1 = *(const half8*)(wfk + (1 << 9));
        half8 wa2 = *(const half8*)(wfk + (2 << 9));
        half8 wa3 = *(const half8*)(wfk + (3 << 9));
        half8 wb0 = *(const half8*)(wfk + (4 << 9)); // cc=1, ot=0
        half8 wb1 = *(const half8*)(wfk + (5 << 9));
        half8 wb2 = *(const half8*)(wfk + (6 << 9));
        half8 wb3 = *(const half8*)(wfk + (7 << 9));

        // gather + interp: the two accumulators are the MFMA B-fragments
        half8 a0 = {0, 0, 0, 0, 0, 0, 0, 0};   // c = cp*8 .. +8      (chunk cc=0)
        half8 a1 = {0, 0, 0, 0, 0, 0, 0, 0};   // c = 32 + cp*8 .. +8 (chunk cc=1)
#pragma unroll
        for (int cr = 0; cr < 8; ++cr) {
            unsigned int vd = vpa[cr >> 1];
            unsigned int voxb = ((cr & 1) ? (vd >> 16) : (vd & 0xffffu)) << 7;
            const char* base = inb + voxb + cpo;
            const half8 v0 = *(const half8*)(base);
            const half8 v1 = *(const half8*)(base + 64);
            unsigned int wd = wpa[cr >> 1];
            unsigned short wu = (cr & 1) ? (unsigned short)(wd >> 16) : (unsigned short)wd;
            _Float16 wh = *(_Float16*)&wu;
            half8 w8 = {wh, wh, wh, wh, wh, wh, wh, wh};
            a0 += v0 * w8;
            a1 += v1 * w8;
        }

        // MFMA: D[o16 x p16] per o-tile, two c-chunks of 32
        acc0 = __builtin_amdgcn_mfma_f32_16x16x32_f16(wa0, a0, acc0, 0, 0, 0);
        acc0 = __builtin_amdgcn_mfma_f32_16x16x32_f16(wb0, a1, acc0, 0, 0, 0);
        acc1 = __builtin_amdgcn_mfma_f32_16x16x32_f16(wa1, a0, acc1, 0, 0, 0);
        acc1 = __builtin_amdgcn_mfma_f32_16x16x32_f16(wb1, a1, acc1, 0, 0, 0);
        acc2 = __builtin_amdgcn_mfma_f32_16x16x32_f16(wa2, a0, acc2, 0, 0, 0);
        acc2 = __builtin_amdgcn_mfma_f32_16x16x32_f16(wb2, a1, acc2, 0, 0, 0);
        acc3 = __builtin_amdgcn_mfma_f32_16x16x32_f16(wa3, a0, acc3, 0, 0, 0);
        acc3 = __builtin_amdgcn_mfma_f32_16x16x32_f16(wb3, a1, acc3, 0, 0, 0);
    }

    // ---- epilogue: o = ot*16 + cp*4 + r ; p = p0 + prow ----
    float* ob = out + (size_t)n * OC * DHW + p0 + prow + (size_t)(cp << 2) * DHW;
#pragma unroll
    for (int r = 0; r < 4; ++r) {
        ob[(size_t)(r +  0) * DHW] = acc0[r];
        ob[(size_t)(r + 16) * DHW] = acc1[r];
        ob[(size_t)(r + 32) * DHW] = acc2[r];
        ob[(size_t)(r + 48) * DHW] = acc3[r];
    }
}

// ---------------------------------------------------------------------------
// Fallback (no workspace): fp32 fused kernel, original layouts.
__global__ __launch_bounds__(256) void k_fallback(const float* __restrict__ inp,
                                                  const float* __restrict__ wt,
                                                  const float* __restrict__ offs,
                                                  float* __restrict__ out) {
    __shared__ float Slds[64][68];
    __shared__ float Wlds[64 * 64];
    int bid = blockIdx.x;
    int n = bid >> 8;
    int p0 = (bid & 255) * 64;
    int t = threadIdx.x;
    int cq = t & 15, c0 = cq << 2, pslot = t >> 4;
    int ob = (t & 15) << 2, pb = (t >> 4) << 2;
    int swz_w = (((cq & 7) ^ (cq >> 3)) << 2);
    float acc[4][4] = {};
    const float* offbase = offs + (size_t)n * (KN_ * 3) * DHW;
    for (int k = 0; k < KN_; ++k) {
#pragma unroll
        for (int i = 0; i < 16; ++i) {
            int f = i * 256 + t;
            int o = f & 63, c = f >> 6;
            Wlds[f] = wt[(o * CC + c) * KN_ + k];
        }
#pragma unroll
        for (int j = 0; j < 4; ++j) {
            int pl = pslot + 16 * j;
            int pa = p0 + pl;
            int d = pa >> 10, h = (pa >> 5) & 31, w = pa & 31;
            float offz = offbase[(k * 3 + 0) * DHW + pa];
            float offy = offbase[(k * 3 + 1) * DHW + pa];
            float offx = offbase[(k * 3 + 2) * DHW + pa];
            float ix = ((float)w + offx) * (32.0f / 31.0f) - 0.5f;
            float iy = ((float)h + offy) * (32.0f / 31.0f) - 0.5f;
            float iz = ((float)d + offz) * (16.0f / 15.0f) - 0.5f;
            float xf = floorf(ix), yf = floorf(iy), zf = floorf(iz);
            float fx = ix - xf, fy = iy - yf, fz = iz - zf;
            int x0 = (int)xf, y0 = (int)yf, z0 = (int)zf;
            float wx0 = 1.0f - fx, wx1 = fx, wy0 = 1.0f - fy, wy1 = fy, wz0 = 1.0f - fz, wz1 = fz;
            float s0 = 0.f, s1 = 0.f, s2 = 0.f, s3 = 0.f;
#pragma unroll
            for (int dz = 0; dz < 2; ++dz) {
                int zc = z0 + dz;
                if ((unsigned)zc >= (unsigned)DD) continue;
                float wz = dz ? wz1 : wz0;
#pragma unroll
                for (int dy = 0; dy < 2; ++dy) {
                    int yc = y0 + dy;
                    if ((unsigned)yc >= (unsigned)HH) continue;
                    float wzy = wz * (dy ? wy1 : wy0);
#pragma unroll
                    for (int dx = 0; dx < 2; ++dx) {
                        int xc = x0 + dx;
                        if ((unsigned)xc >= (unsigned)WW) continue;
                        float wf = wzy * (dx ? wx1 : wx0);
                        int vox = (zc * HH + yc) * WW + xc;
                        const float* b = inp + (size_t)(n * CC + c0) * DHW + vox;
                        s0 += wf * b[0]; s1 += wf * b[DHW];
                        s2 += wf * b[2 * DHW]; s3 += wf * b[3 * DHW];
                    }
                }
            }
            int plw = pl ^ swz_w;
            Slds[c0 + 0][plw] = s0; Slds[c0 + 1][plw] = s1;
            Slds[c0 + 2][plw] = s2; Slds[c0 + 3][plw] = s3;
        }
        __syncthreads();
#pragma unroll
        for (int c = 0; c < 64; ++c) {
            const int g = ((c >> 2) & 7) ^ (c >> 5);
            float4 wv = *(const float4*)(Wlds + c * 64 + ob);
            float4 sv = *(const float4*)(&Slds[c][pb ^ (g << 2)]);
            float wa[4] = {wv.x, wv.y, wv.z, wv.w};
            float sa[4] = {sv.x, sv.y, sv.z, sv.w};
#pragma unroll
            for (int i = 0; i < 4; ++i)
#pragma unroll
                for (int jj = 0; jj < 4; ++jj) acc[i][jj] += wa[i] * sa[jj];
        }
        __syncthreads();
    }
#pragma unroll
    for (int i = 0; i < 4; ++i) {
        float4 vv;
        vv.x = acc[i][0]; vv.y = acc[i][1]; vv.z = acc[i][2]; vv.w = acc[i][3];
        *(float4*)(out + (size_t)(n * OC + ob + i) * DHW + p0 + pb) = vv;
    }
}

// ---------------------------------------------------------------------------
extern "C" void kernel_launch(void* const* d_in, const int* in_sizes, int n_in,
                              void* d_out, int out_size, void* d_ws, size_t ws_size,
                              hipStream_t stream) {
    const float* inp = (const float*)d_in[0];
    const float* off = (const float*)d_in[1];
    const float* wgt = (const float*)d_in[2];
    float* out = (float*)d_out;

    const size_t in_f16_bytes = (size_t)NB * DHW * CC * 2;           // 4 MB
    const size_t wf_bytes     = (size_t)KN_ * 2 * 4 * 64 * 8 * 2;    // 216 KB

    if (ws_size >= in_f16_bytes + wf_bytes) {
        unsigned int*   in_t = (unsigned int*)d_ws;
        unsigned short* w_f  = (unsigned short*)((char*)d_ws + in_f16_bytes);
        k_prep<<<dim3(512 + 432), dim3(256), 0, stream>>>(inp, wgt, in_t, w_f);
        k_main<<<dim3(2048), dim3(64), 0, stream>>>(
            (const unsigned short*)in_t, w_f, off, out);
    } else {
        k_fallback<<<dim3(NB * 256), dim3(256), 0, stream>>>(inp, wgt, off, out);
    }
}

// Round 8
// 181.530 us; speedup vs baseline: 1.0011x; 1.0011x over previous
//
#include <hip/hip_runtime.h>

typedef __attribute__((ext_vector_type(8))) _Float16 half8;
typedef __attribute__((ext_vector_type(4))) float floatx4;

constexpr int NB  = 2;
constexpr int CC  = 64;
constexpr int DD  = 16;
constexpr int HH  = 32;
constexpr int WW  = 32;
constexpr int KN_ = 27;
constexpr int OC  = 64;
constexpr int DHW = DD * HH * WW;   // 16384
constexpr int TP  = 16;             // positions per block tile

__device__ __forceinline__ unsigned short f2h(float f) {
    _Float16 h = (_Float16)f;
    return *(unsigned short*)&h;
}

// ---------------------------------------------------------------------------
// Prep kernel (merged):
//  blocks [0, 512)   : NCDHW f32 -> NDHWC f16  (64 ch contiguous per voxel)
//  blocks [512, 944) : weight (o,c,k) f32 -> f16 MFMA A-fragment stream
//    wf[(((k*2+cc)*4+ot)*64 + l)*8 + i] = W[o=ot*16+(l&15)][c=cc*32+(l>>4)*8+i][k]
__global__ __launch_bounds__(256) void k_prep(const float* __restrict__ in,
                                              const float* __restrict__ w,
                                              unsigned int* __restrict__ outu,
                                              unsigned short* __restrict__ wf) {
    int bid = blockIdx.x;
    int t = threadIdx.x;
    if (bid < 512) {
        __shared__ float tile[64][65];
        int n  = bid >> 8;
        int v0 = (bid & 255) << 6;
        int lane = t & 63, row = t >> 6;
#pragma unroll
        for (int i = 0; i < 16; ++i) {
            int c = (i << 2) + row;
            tile[c][lane] = in[(size_t)(n * CC + c) * DHW + v0 + lane];
        }
        __syncthreads();
#pragma unroll
        for (int i = 0; i < 8; ++i) {
            int flat = i * 256 + t;
            int v = flat >> 5, cd = flat & 31;
            unsigned int lo = f2h(tile[2 * cd][v]);
            unsigned int hi = f2h(tile[2 * cd + 1][v]);
            outu[(size_t)(n * DHW + v0 + v) * 32 + cd] = lo | (hi << 16);
        }
    } else {
        int f = (bid - 512) * 256 + t;   // 110592 total
        int i  = f & 7;
        int l  = (f >> 3) & 63;
        int ot = (f >> 9) & 3;
        int cc = (f >> 11) & 1;
        int k  = f >> 12;
        int o = ot * 16 + (l & 15);
        int c = cc * 32 + ((l >> 4) << 3) + i;
        wf[f] = f2h(w[(o * CC + c) * KN_ + k]);
    }
}

// ---------------------------------------------------------------------------
// Tap-split barrier-free deformable conv.
// 256 threads (4 waves) per block; block = 16 positions, all 64 outputs.
// Wave w handles taps k ≡ w (mod 4); main loop has NO barriers.
// Lane l: position prow=l&15, channel chunks cp=(l>>4)*8 and 32+(l>>4)*8;
// interp accumulators ARE the MFMA B-fragments (no S staging).
// Epilogue: 4 rounds of LDS stage + 4-wave sum + coalesced store.
__global__ __launch_bounds__(256, 5) void k_main(const unsigned short* __restrict__ inp,
                                                 const unsigned short* __restrict__ wf,
                                                 const float* __restrict__ offs,
                                                 float* __restrict__ out) {
    __shared__ uint4 SUV[KN_ * TP];   // 432 recs: 8 x u16 voxel ids      (6.9KB)
    __shared__ uint4 SUW[KN_ * TP];   // 432 recs: 8 x f16 corner weights (6.9KB)
    __shared__ float E[4][16][17];    // epilogue partials (4.4KB, padded)

    int t   = threadIdx.x;
    int bid = blockIdx.x;
    int n   = (bid >> 2) & 1;                      // XCDs 0-3 -> n=0, 4-7 -> n=1
    int idx = ((bid >> 3) << 2) | (bid & 3);       // 0..1023
    int p0  = idx << 4;

    const float* offb = offs + (size_t)n * (3 * KN_) * DHW + p0;
    const char*  inb  = (const char*)(inp + ((size_t)n * DHW << 6));

    // ---- setup: 432 (k,p) sampling records, coordinate math once each ----
    for (int si = t; si < KN_ * TP; si += 256) {
        int k = si >> 4, p = si & 15;
        int pa = p0 + p;
        int dpos = pa >> 10, hpos = (pa >> 5) & 31, wpos = pa & 31;

        float oz = offb[(k * 3 + 0) * DHW + p];
        float oy = offb[(k * 3 + 1) * DHW + p];
        float ox = offb[(k * 3 + 2) * DHW + p];
        float ix = ((float)wpos + ox) * (32.0f / 31.0f) - 0.5f;
        float iy = ((float)hpos + oy) * (32.0f / 31.0f) - 0.5f;
        float iz = ((float)dpos + oz) * (16.0f / 15.0f) - 0.5f;
        float xf = floorf(ix), yf = floorf(iy), zf = floorf(iz);
        float fx = ix - xf, fy = iy - yf, fz = iz - zf;
        int x0 = (int)xf, y0 = (int)yf, z0 = (int)zf;

        float wx0 = ((unsigned)x0       < (unsigned)WW) ? 1.f - fx : 0.f;
        float wx1 = ((unsigned)(x0 + 1) < (unsigned)WW) ? fx       : 0.f;
        float wy0 = ((unsigned)y0       < (unsigned)HH) ? 1.f - fy : 0.f;
        float wy1 = ((unsigned)(y0 + 1) < (unsigned)HH) ? fy       : 0.f;
        float wz0 = ((unsigned)z0       < (unsigned)DD) ? 1.f - fz : 0.f;
        float wz1 = ((unsigned)(z0 + 1) < (unsigned)DD) ? fz       : 0.f;

        int xc0 = min(max(x0, 0), WW - 1), xc1 = min(max(x0 + 1, 0), WW - 1);
        int yc0 = min(max(y0, 0), HH - 1), yc1 = min(max(y0 + 1, 0), HH - 1);
        int zc0 = min(max(z0, 0), DD - 1), zc1 = min(max(z0 + 1, 0), DD - 1);

        float wzy00 = wz0 * wy0, wzy01 = wz0 * wy1, wzy10 = wz1 * wy0, wzy11 = wz1 * wy1;
        unsigned int b00 = (zc0 * HH + yc0) * WW, b01 = (zc0 * HH + yc1) * WW;
        unsigned int b10 = (zc1 * HH + yc0) * WW, b11 = (zc1 * HH + yc1) * WW;

        uint4 vp, wp;
        vp.x = (b00 + xc0) | ((b00 + xc1) << 16);
        vp.y = (b01 + xc0) | ((b01 + xc1) << 16);
        vp.z = (b10 + xc0) | ((b10 + xc1) << 16);
        vp.w = (b11 + xc0) | ((b11 + xc1) << 16);
        wp.x = (unsigned int)f2h(wzy00 * wx0) | ((unsigned int)f2h(wzy00 * wx1) << 16);
        wp.y = (unsigned int)f2h(wzy01 * wx0) | ((unsigned int)f2h(wzy01 * wx1) << 16);
        wp.z = (unsigned int)f2h(wzy10 * wx0) | ((unsigned int)f2h(wzy10 * wx1) << 16);
        wp.w = (unsigned int)f2h(wzy11 * wx0) | ((unsigned int)f2h(wzy11 * wx1) << 16);

        SUV[si] = vp;
        SUW[si] = wp;
    }
    __syncthreads();

    const int w    = t >> 6;          // wave id -> tap residue class
    const int l    = t & 63;
    const int prow = l & 15;          // position in tile == MFMA col
    const int cp   = l >> 4;          // channel chunk pair: cp and cp+4
    const int cpo  = cp << 4;         // byte offset of chunk cp in 128B voxel row

    floatx4 acc0 = {0.f, 0.f, 0.f, 0.f};
    floatx4 acc1 = {0.f, 0.f, 0.f, 0.f};
    floatx4 acc2 = {0.f, 0.f, 0.f, 0.f};
    floatx4 acc3 = {0.f, 0.f, 0.f, 0.f};

    // ---- main loop: wave-private, BARRIER-FREE ----
    for (int k = w; k < KN_; k += 4) {
        // sampling record (broadcast across the 4 lanes sharing a position)
        const uint4 vp = SUV[(k << 4) + prow];
        const uint4 wp = SUW[(k << 4) + prow];
        const unsigned int vpa[4] = {vp.x, vp.y, vp.z, vp.w};
        const unsigned int wpa[4] = {wp.x, wp.y, wp.z, wp.w};

        // A fragments for this tap (8 x 16B, L2-resident stream)
        const unsigned short* wfk = wf + ((size_t)(k << 3) << 9) + (l << 3);
        half8 wa0 = *(const half8*)(wfk);            // cc=0, ot=0..3
        half8 wa1 = *(const half8*)(wfk + (1 << 9));
        half8 wa2 = *(const half8*)(wfk + (2 << 9));
        half8 wa3 = *(const half8*)(wfk + (3 << 9));
        half8 wb0 = *(const half8*)(wfk + (4 << 9)); // cc=1, ot=0..3
        half8 wb1 = *(const half8*)(wfk + (5 << 9));
        half8 wb2 = *(const half8*)(wfk + (6 << 9));
        half8 wb3 = *(const half8*)(wfk + (7 << 9));

        // gather + interp: the two accumulators are the MFMA B-fragments
        half8 a0 = {0, 0, 0, 0, 0, 0, 0, 0};   // c = cp*8 .. +8
        half8 a1 = {0, 0, 0, 0, 0, 0, 0, 0};   // c = 32 + cp*8 .. +8
#pragma unroll
        for (int cr = 0; cr < 8; ++cr) {
            unsigned int vd = vpa[cr >> 1];
            unsigned int voxb = ((cr & 1) ? (vd >> 16) : (vd & 0xffffu)) << 7;
            const char* base = inb + voxb + cpo;
            const half8 v0 = *(const half8*)(base);
            const half8 v1 = *(const half8*)(base + 64);
            unsigned int wd = wpa[cr >> 1];
            unsigned short wu = (cr & 1) ? (unsigned short)(wd >> 16) : (unsigned short)wd;
            _Float16 wh = *(_Float16*)&wu;
            half8 w8 = {wh, wh, wh, wh, wh, wh, wh, wh};
            a0 += v0 * w8;
            a1 += v1 * w8;
        }

        // MFMA: D[o16 x p16] per o-tile, two c-chunks of 32
        acc0 = __builtin_amdgcn_mfma_f32_16x16x32_f16(wa0, a0, acc0, 0, 0, 0);
        acc0 = __builtin_amdgcn_mfma_f32_16x16x32_f16(wb0, a1, acc0, 0, 0, 0);
        acc1 = __builtin_amdgcn_mfma_f32_16x16x32_f16(wa1, a0, acc1, 0, 0, 0);
        acc1 = __builtin_amdgcn_mfma_f32_16x16x32_f16(wb1, a1, acc1, 0, 0, 0);
        acc2 = __builtin_amdgcn_mfma_f32_16x16x32_f16(wa2, a0, acc2, 0, 0, 0);
        acc2 = __builtin_amdgcn_mfma_f32_16x16x32_f16(wb2, a1, acc2, 0, 0, 0);
        acc3 = __builtin_amdgcn_mfma_f32_16x16x32_f16(wa3, a0, acc3, 0, 0, 0);
        acc3 = __builtin_amdgcn_mfma_f32_16x16x32_f16(wb3, a1, acc3, 0, 0, 0);
    }

    // ---- epilogue: 4 rounds of cross-wave reduce through LDS ----
    // acc_ot[r] holds partial out[o = ot*16 + cp*4 + r][p0 + prow] for this wave's taps.
#define EPI_ROUND(ACC, OT)                                                    \
    E[w][(cp << 2) + 0][prow] = ACC[0];                                       \
    E[w][(cp << 2) + 1][prow] = ACC[1];                                       \
    E[w][(cp << 2) + 2][prow] = ACC[2];                                       \
    E[w][(cp << 2) + 3][prow] = ACC[3];                                       \
    __syncthreads();                                                          \
    {   int oo = t >> 4, pp = t & 15;                                         \
        float s = E[0][oo][pp] + E[1][oo][pp] + E[2][oo][pp] + E[3][oo][pp];  \
        out[((size_t)n * OC + (OT) * 16 + oo) * DHW + p0 + pp] = s; }         \
    __syncthreads();

    EPI_ROUND(acc0, 0)
    EPI_ROUND(acc1, 1)
    EPI_ROUND(acc2, 2)
    EPI_ROUND(acc3, 3)
#undef EPI_ROUND
}

// ---------------------------------------------------------------------------
// Fallback (no workspace): fp32 fused kernel, original layouts.
__global__ __launch_bounds__(256) void k_fallback(const float* __restrict__ inp,
                                                  const float* __restrict__ wt,
                                                  const float* __restrict__ offs,
                                                  float* __restrict__ out) {
    __shared__ float Slds[64][68];
    __shared__ float Wlds[64 * 64];
    int bid = blockIdx.x;
    int n = bid >> 8;
    int p0 = (bid & 255) * 64;
    int t = threadIdx.x;
    int cq = t & 15, c0 = cq << 2, pslot = t >> 4;
    int ob = (t & 15) << 2, pb = (t >> 4) << 2;
    int swz_w = (((cq & 7) ^ (cq >> 3)) << 2);
    float acc[4][4] = {};
    const float* offbase = offs + (size_t)n * (KN_ * 3) * DHW;
    for (int k = 0; k < KN_; ++k) {
#pragma unroll
        for (int i = 0; i < 16; ++i) {
            int f = i * 256 + t;
            int o = f & 63, c = f >> 6;
            Wlds[f] = wt[(o * CC + c) * KN_ + k];
        }
#pragma unroll
        for (int j = 0; j < 4; ++j) {
            int pl = pslot + 16 * j;
            int pa = p0 + pl;
            int d = pa >> 10, h = (pa >> 5) & 31, w = pa & 31;
            float offz = offbase[(k * 3 + 0) * DHW + pa];
            float offy = offbase[(k * 3 + 1) * DHW + pa];
            float offx = offbase[(k * 3 + 2) * DHW + pa];
            float ix = ((float)w + offx) * (32.0f / 31.0f) - 0.5f;
            float iy = ((float)h + offy) * (32.0f / 31.0f) - 0.5f;
            float iz = ((float)d + offz) * (16.0f / 15.0f) - 0.5f;
            float xf = floorf(ix), yf = floorf(iy), zf = floorf(iz);
            float fx = ix - xf, fy = iy - yf, fz = iz - zf;
            int x0 = (int)xf, y0 = (int)yf, z0 = (int)zf;
            float wx0 = 1.0f - fx, wx1 = fx, wy0 = 1.0f - fy, wy1 = fy, wz0 = 1.0f - fz, wz1 = fz;
            float s0 = 0.f, s1 = 0.f, s2 = 0.f, s3 = 0.f;
#pragma unroll
            for (int dz = 0; dz < 2; ++dz) {
                int zc = z0 + dz;
                if ((unsigned)zc >= (unsigned)DD) continue;
                float wz = dz ? wz1 : wz0;
#pragma unroll
                for (int dy = 0; dy < 2; ++dy) {
                    int yc = y0 + dy;
                    if ((unsigned)yc >= (unsigned)HH) continue;
                    float wzy = wz * (dy ? wy1 : wy0);
#pragma unroll
                    for (int dx = 0; dx < 2; ++dx) {
                        int xc = x0 + dx;
                        if ((unsigned)xc >= (unsigned)WW) continue;
                        float wf = wzy * (dx ? wx1 : wx0);
                        int vox = (zc * HH + yc) * WW + xc;
                        const float* b = inp + (size_t)(n * CC + c0) * DHW + vox;
                        s0 += wf * b[0]; s1 += wf * b[DHW];
                        s2 += wf * b[2 * DHW]; s3 += wf * b[3 * DHW];
                    }
                }
            }
            int plw = pl ^ swz_w;
            Slds[c0 + 0][plw] = s0; Slds[c0 + 1][plw] = s1;
            Slds[c0 + 2][plw] = s2; Slds[c0 + 3][plw] = s3;
        }
        __syncthreads();
#pragma unroll
        for (int c = 0; c < 64; ++c) {
            const int g = ((c >> 2) & 7) ^ (c >> 5);
            float4 wv = *(const float4*)(Wlds + c * 64 + ob);
            float4 sv = *(const float4*)(&Slds[c][pb ^ (g << 2)]);
            float wa[4] = {wv.x, wv.y, wv.z, wv.w};
            float sa[4] = {sv.x, sv.y, sv.z, sv.w};
#pragma unroll
            for (int i = 0; i < 4; ++i)
#pragma unroll
                for (int jj = 0; jj < 4; ++jj) acc[i][jj] += wa[i] * sa[jj];
        }
        __syncthreads();
    }
#pragma unroll
    for (int i = 0; i < 4; ++i) {
        float4 vv;
        vv.x = acc[i][0]; vv.y = acc[i][1]; vv.z = acc[i][2]; vv.w = acc[i][3];
        *(float4*)(out + (size_t)(n * OC + ob + i) * DHW + p0 + pb) = vv;
    }
}

// ---------------------------------------------------------------------------
extern "C" void kernel_launch(void* const* d_in, const int* in_sizes, int n_in,
                              void* d_out, int out_size, void* d_ws, size_t ws_size,
                              hipStream_t stream) {
    const float* inp = (const float*)d_in[0];
    const float* off = (const float*)d_in[1];
    const float* wgt = (const float*)d_in[2];
    float* out = (float*)d_out;

    const size_t in_f16_bytes = (size_t)NB * DHW * CC * 2;           // 4 MB
    const size_t wf_bytes     = (size_t)KN_ * 2 * 4 * 64 * 8 * 2;    // 216 KB

    if (ws_size >= in_f16_bytes + wf_bytes) {
        unsigned int*   in_t = (unsigned int*)d_ws;
        unsigned short* w_f  = (unsigned short*)((char*)d_ws + in_f16_bytes);
        k_prep<<<dim3(512 + 432), dim3(256), 0, stream>>>(inp, wgt, in_t, w_f);
        k_main<<<dim3(2048), dim3(256), 0, stream>>>(
            (const unsigned short*)in_t, w_f, off, out);
    } else {
        k_fallback<<<dim3(NB * 256), dim3(256), 0, stream>>>(inp, wgt, off, out);
    }
}

// Round 9
// 119.912 us; speedup vs baseline: 1.5156x; 1.5139x over previous
//
#include <hip/hip_runtime.h>

typedef __attribute__((ext_vector_type(8))) _Float16 half8;
typedef __attribute__((ext_vector_type(4))) float floatx4;

constexpr int NB  = 2;
constexpr int CC  = 64;
constexpr int DD  = 16;
constexpr int HH  = 32;
constexpr int WW  = 32;
constexpr int KN_ = 27;
constexpr int KSP = 14;             // tap-split: [0,14) / [14,27)
constexpr int OC  = 64;
constexpr int DHW = DD * HH * WW;   // 16384
constexpr int TP  = 16;             // positions per block tile

__device__ __forceinline__ unsigned short f2h(float f) {
    _Float16 h = (_Float16)f;
    return *(unsigned short*)&h;
}

// ---------------------------------------------------------------------------
// Prep kernel (merged):
//  blocks [0, 512)      : NCDHW f32 -> NDHWC f16  (64 ch contiguous per voxel)
//  blocks [512, 944)    : weight (o,c,k) f32 -> f16 MFMA A-fragment stream
//  blocks [944, 2992)   : zero-fill d_out (atomic accumulation target)
__global__ __launch_bounds__(256) void k_prep(const float* __restrict__ in,
                                              const float* __restrict__ w,
                                              unsigned int* __restrict__ outu,
                                              unsigned short* __restrict__ wf,
                                              float4* __restrict__ outz) {
    int bid = blockIdx.x;
    int t = threadIdx.x;
    if (bid < 512) {
        __shared__ float tile[64][65];
        int n  = bid >> 8;
        int v0 = (bid & 255) << 6;
        int lane = t & 63, row = t >> 6;
#pragma unroll
        for (int i = 0; i < 16; ++i) {
            int c = (i << 2) + row;
            tile[c][lane] = in[(size_t)(n * CC + c) * DHW + v0 + lane];
        }
        __syncthreads();
#pragma unroll
        for (int i = 0; i < 8; ++i) {
            int flat = i * 256 + t;
            int v = flat >> 5, cd = flat & 31;
            unsigned int lo = f2h(tile[2 * cd][v]);
            unsigned int hi = f2h(tile[2 * cd + 1][v]);
            outu[(size_t)(n * DHW + v0 + v) * 32 + cd] = lo | (hi << 16);
        }
    } else if (bid < 944) {
        int f = (bid - 512) * 256 + t;   // 110592 total
        int i  = f & 7;
        int l  = (f >> 3) & 63;
        int ot = (f >> 9) & 3;
        int cc = (f >> 11) & 1;
        int k  = f >> 12;
        int o = ot * 16 + (l & 15);
        int c = cc * 32 + ((l >> 4) << 3) + i;
        wf[f] = f2h(w[(o * CC + c) * KN_ + k]);
    } else {
        float4 z = {0.f, 0.f, 0.f, 0.f};
        outz[(bid - 944) * 256 + t] = z;   // 2048 blocks x 256 x 16B = 8MB
    }
}

// ---------------------------------------------------------------------------
// Tap-split lockstep deformable conv (r5 core).
// 4096 blocks x 128 threads (2 waves). Block = 16 positions, tap half h:
// h=0 -> k in [0,14), h=1 -> k in [14,27). Results atomicAdd'ed into out.
// Sampling: sp=t>>3 (16 pos), cg=t&7 (8ch chunk); setup records in LDS.
// MFMA: wave wv handles o-tiles 2*wv, 2*wv+1.
__global__ __launch_bounds__(128, 8) void k_main(const unsigned short* __restrict__ inp,
                                                 const unsigned short* __restrict__ wf,
                                                 const float* __restrict__ offs,
                                                 float* __restrict__ out) {
    __shared__ unsigned short S[2 * TP * 64];   // 4KB dbuf [buf][p][c] f16, chunk-XOR swz
    __shared__ uint4 SUV[KSP * TP];             // up to 14 taps: 8 x u16 voxel ids  (3.5KB)
    __shared__ uint4 SUW[KSP * TP];             // 8 x f16 corner weights            (3.5KB)

    int t   = threadIdx.x;
    int bid = blockIdx.x;
    int n   = (bid >> 2) & 1;                   // XCDs 0-3 -> n=0, 4-7 -> n=1
    int h   = (bid >> 3) & 1;                   // tap half
    int idx = ((bid >> 4) << 2) | (bid & 3);    // 0..1023
    int p0  = idx << 4;
    int k0  = h ? KSP : 0;
    int nk  = h ? (KN_ - KSP) : KSP;            // 13 or 14

    int sp = t >> 3;            // 0..15 position in tile
    int cg = t & 7;             // channel chunk (16B of 128B voxel row)
    int wv = t >> 6;            // wave id (o-tile pair)
    int l  = t & 63;
    int lrow = l & 15, lk = l >> 4;

    const float* offb = offs + (size_t)n * (3 * KN_) * DHW + p0;
    const char*  inb  = (const char*)(inp + ((size_t)n * DHW << 6));

    floatx4 acc0 = {0.f, 0.f, 0.f, 0.f};
    floatx4 acc1 = {0.f, 0.f, 0.f, 0.f};

    const int cgo   = cg << 4;
    const int woff  = sp * 64 + ((cg ^ (sp & 7)) << 3);            // ushort units
    const int roff0 = lrow * 64 + (((0 | lk) ^ (lrow & 7)) << 3);
    const int roff1 = lrow * 64 + (((4 | lk) ^ (lrow & 7)) << 3);

    // ---- setup: nk*16 sampling records, coordinate math once each ----
    for (int si = t; si < nk * TP; si += 128) {
        int krel = si >> 4, p = si & 15;
        int k  = k0 + krel;
        int pa = p0 + p;
        int dpos = pa >> 10, hpos = (pa >> 5) & 31, wpos = pa & 31;

        float oz = offb[(k * 3 + 0) * DHW + p];
        float oy = offb[(k * 3 + 1) * DHW + p];
        float ox = offb[(k * 3 + 2) * DHW + p];
        float ix = ((float)wpos + ox) * (32.0f / 31.0f) - 0.5f;
        float iy = ((float)hpos + oy) * (32.0f / 31.0f) - 0.5f;
        float iz = ((float)dpos + oz) * (16.0f / 15.0f) - 0.5f;
        float xf = floorf(ix), yf = floorf(iy), zf = floorf(iz);
        float fx = ix - xf, fy = iy - yf, fz = iz - zf;
        int x0 = (int)xf, y0 = (int)yf, z0 = (int)zf;

        float wx0 = ((unsigned)x0       < (unsigned)WW) ? 1.f - fx : 0.f;
        float wx1 = ((unsigned)(x0 + 1) < (unsigned)WW) ? fx       : 0.f;
        float wy0 = ((unsigned)y0       < (unsigned)HH) ? 1.f - fy : 0.f;
        float wy1 = ((unsigned)(y0 + 1) < (unsigned)HH) ? fy       : 0.f;
        float wz0 = ((unsigned)z0       < (unsigned)DD) ? 1.f - fz : 0.f;
        float wz1 = ((unsigned)(z0 + 1) < (unsigned)DD) ? fz       : 0.f;

        int xc0 = min(max(x0, 0), WW - 1), xc1 = min(max(x0 + 1, 0), WW - 1);
        int yc0 = min(max(y0, 0), HH - 1), yc1 = min(max(y0 + 1, 0), HH - 1);
        int zc0 = min(max(z0, 0), DD - 1), zc1 = min(max(z0 + 1, 0), DD - 1);

        float wzy00 = wz0 * wy0, wzy01 = wz0 * wy1, wzy10 = wz1 * wy0, wzy11 = wz1 * wy1;
        unsigned int b00 = (zc0 * HH + yc0) * WW, b01 = (zc0 * HH + yc1) * WW;
        unsigned int b10 = (zc1 * HH + yc0) * WW, b11 = (zc1 * HH + yc1) * WW;

        uint4 vp, wp;
        vp.x = (b00 + xc0) | ((b00 + xc1) << 16);
        vp.y = (b01 + xc0) | ((b01 + xc1) << 16);
        vp.z = (b10 + xc0) | ((b10 + xc1) << 16);
        vp.w = (b11 + xc0) | ((b11 + xc1) << 16);
        wp.x = (unsigned int)f2h(wzy00 * wx0) | ((unsigned int)f2h(wzy00 * wx1) << 16);
        wp.y = (unsigned int)f2h(wzy01 * wx0) | ((unsigned int)f2h(wzy01 * wx1) << 16);
        wp.z = (unsigned int)f2h(wzy10 * wx0) | ((unsigned int)f2h(wzy10 * wx1) << 16);
        wp.w = (unsigned int)f2h(wzy11 * wx0) | ((unsigned int)f2h(wzy11 * wx1) << 16);

        SUV[si] = vp;
        SUW[si] = wp;
    }
    __syncthreads();

    // ---- lockstep per-tap loop (r5 core) ----
    for (int krel = 0; krel < nk; ++krel) {
        int k = k0 + krel;

        // W fragments (L2-resident stream; issue early)
        const half8 wa00 = *(const half8*)(wf + ((((k << 1) | 0) * 4 + (wv << 1) + 0) << 9) + (l << 3));
        const half8 wa01 = *(const half8*)(wf + ((((k << 1) | 1) * 4 + (wv << 1) + 0) << 9) + (l << 3));
        const half8 wa10 = *(const half8*)(wf + ((((k << 1) | 0) * 4 + (wv << 1) + 1) << 9) + (l << 3));
        const half8 wa11 = *(const half8*)(wf + ((((k << 1) | 1) * 4 + (wv << 1) + 1) << 9) + (l << 3));

        // setup record (8 lanes of a position-group broadcast-read 32B)
        const uint4 vp = SUV[(krel << 4) + sp];
        const uint4 wp = SUW[(krel << 4) + sp];
        const unsigned int vpa[4] = {vp.x, vp.y, vp.z, vp.w};
        const unsigned int wpa[4] = {wp.x, wp.y, wp.z, wp.w};

        half8 accv = {0, 0, 0, 0, 0, 0, 0, 0};
#pragma unroll
        for (int cr = 0; cr < 8; ++cr) {
            unsigned int vd = vpa[cr >> 1];
            unsigned int voxb = ((cr & 1) ? (vd >> 16) : (vd & 0xffffu)) << 7;
            unsigned int wd = wpa[cr >> 1];
            unsigned short wu = (cr & 1) ? (unsigned short)(wd >> 16) : (unsigned short)wd;
            _Float16 wh = *(_Float16*)&wu;
            const half8 v = *(const half8*)(inb + voxb + cgo);
            half8 w8 = {wh, wh, wh, wh, wh, wh, wh, wh};
            accv += v * w8;                      // 4x v_pk_fma_f16
        }
        *(half8*)(S + ((krel & 1) << 10) + woff) = accv;

        __syncthreads();

        // MFMA: D[o16 x p16] += A(o x c) * B(c x p), two c-chunks of 32
        const unsigned short* Sb = S + ((krel & 1) << 10);
        const half8 bf0 = *(const half8*)(Sb + roff0);
        const half8 bf1 = *(const half8*)(Sb + roff1);
        acc0 = __builtin_amdgcn_mfma_f32_16x16x32_f16(wa00, bf0, acc0, 0, 0, 0);
        acc0 = __builtin_amdgcn_mfma_f32_16x16x32_f16(wa01, bf1, acc0, 0, 0, 0);
        acc1 = __builtin_amdgcn_mfma_f32_16x16x32_f16(wa10, bf0, acc1, 0, 0, 0);
        acc1 = __builtin_amdgcn_mfma_f32_16x16x32_f16(wa11, bf1, acc1, 0, 0, 0);
        // dbuf S: next iteration's barrier orders reads vs krel+2 overwrite
    }

    // ---- epilogue: atomic accumulate (2 halves per output element) ----
    // o = wv*32 + (acc sel)*16 + lk*4 + r ; p = p0 + lrow
    float* ob = out + ((size_t)n * OC + (wv << 5) + (lk << 2)) * DHW + p0 + lrow;
#pragma unroll
    for (int r = 0; r < 4; ++r) {
        atomicAdd(&ob[r * DHW], acc0[r]);
        atomicAdd(&ob[r * DHW + (DHW << 4)], acc1[r]);
    }
}

// ---------------------------------------------------------------------------
// Fallback (no workspace): fp32 fused kernel, original layouts.
__global__ __launch_bounds__(256) void k_fallback(const float* __restrict__ inp,
                                                  const float* __restrict__ wt,
                                                  const float* __restrict__ offs,
                                                  float* __restrict__ out) {
    __shared__ float Slds[64][68];
    __shared__ float Wlds[64 * 64];
    int bid = blockIdx.x;
    int n = bid >> 8;
    int p0 = (bid & 255) * 64;
    int t = threadIdx.x;
    int cq = t & 15, c0 = cq << 2, pslot = t >> 4;
    int ob = (t & 15) << 2, pb = (t >> 4) << 2;
    int swz_w = (((cq & 7) ^ (cq >> 3)) << 2);
    float acc[4][4] = {};
    const float* offbase = offs + (size_t)n * (KN_ * 3) * DHW;
    for (int k = 0; k < KN_; ++k) {
#pragma unroll
        for (int i = 0; i < 16; ++i) {
            int f = i * 256 + t;
            int o = f & 63, c = f >> 6;
            Wlds[f] = wt[(o * CC + c) * KN_ + k];
        }
#pragma unroll
        for (int j = 0; j < 4; ++j) {
            int pl = pslot + 16 * j;
            int pa = p0 + pl;
            int d = pa >> 10, h = (pa >> 5) & 31, w = pa & 31;
            float offz = offbase[(k * 3 + 0) * DHW + pa];
            float offy = offbase[(k * 3 + 1) * DHW + pa];
            float offx = offbase[(k * 3 + 2) * DHW + pa];
            float ix = ((float)w + offx) * (32.0f / 31.0f) - 0.5f;
            float iy = ((float)h + offy) * (32.0f / 31.0f) - 0.5f;
            float iz = ((float)d + offz) * (16.0f / 15.0f) - 0.5f;
            float xf = floorf(ix), yf = floorf(iy), zf = floorf(iz);
            float fx = ix - xf, fy = iy - yf, fz = iz - zf;
            int x0 = (int)xf, y0 = (int)yf, z0 = (int)zf;
            float wx0 = 1.0f - fx, wx1 = fx, wy0 = 1.0f - fy, wy1 = fy, wz0 = 1.0f - fz, wz1 = fz;
            float s0 = 0.f, s1 = 0.f, s2 = 0.f, s3 = 0.f;
#pragma unroll
            for (int dz = 0; dz < 2; ++dz) {
                int zc = z0 + dz;
                if ((unsigned)zc >= (unsigned)DD) continue;
                float wz = dz ? wz1 : wz0;
#pragma unroll
                for (int dy = 0; dy < 2; ++dy) {
                    int yc = y0 + dy;
                    if ((unsigned)yc >= (unsigned)HH) continue;
                    float wzy = wz * (dy ? wy1 : wy0);
#pragma unroll
                    for (int dx = 0; dx < 2; ++dx) {
                        int xc = x0 + dx;
                        if ((unsigned)xc >= (unsigned)WW) continue;
                        float wf = wzy * (dx ? wx1 : wx0);
                        int vox = (zc * HH + yc) * WW + xc;
                        const float* b = inp + (size_t)(n * CC + c0) * DHW + vox;
                        s0 += wf * b[0]; s1 += wf * b[DHW];
                        s2 += wf * b[2 * DHW]; s3 += wf * b[3 * DHW];
                    }
                }
            }
            int plw = pl ^ swz_w;
            Slds[c0 + 0][plw] = s0; Slds[c0 + 1][plw] = s1;
            Slds[c0 + 2][plw] = s2; Slds[c0 + 3][plw] = s3;
        }
        __syncthreads();
#pragma unroll
        for (int c = 0; c < 64; ++c) {
            const int g = ((c >> 2) & 7) ^ (c >> 5);
            float4 wv = *(const float4*)(Wlds + c * 64 + ob);
            float4 sv = *(const float4*)(&Slds[c][pb ^ (g << 2)]);
            float wa[4] = {wv.x, wv.y, wv.z, wv.w};
            float sa[4] = {sv.x, sv.y, sv.z, sv.w};
#pragma unroll
            for (int i = 0; i < 4; ++i)
#pragma unroll
                for (int jj = 0; jj < 4; ++jj) acc[i][jj] += wa[i] * sa[jj];
        }
        __syncthreads();
    }
#pragma unroll
    for (int i = 0; i < 4; ++i) {
        float4 vv;
        vv.x = acc[i][0]; vv.y = acc[i][1]; vv.z = acc[i][2]; vv.w = acc[i][3];
        *(float4*)(out + (size_t)(n * OC + ob + i) * DHW + p0 + pb) = vv;
    }
}

// ---------------------------------------------------------------------------
extern "C" void kernel_launch(void* const* d_in, const int* in_sizes, int n_in,
                              void* d_out, int out_size, void* d_ws, size_t ws_size,
                              hipStream_t stream) {
    const float* inp = (const float*)d_in[0];
    const float* off = (const float*)d_in[1];
    const float* wgt = (const float*)d_in[2];
    float* out = (float*)d_out;

    const size_t in_f16_bytes = (size_t)NB * DHW * CC * 2;           // 4 MB
    const size_t wf_bytes     = (size_t)KN_ * 2 * 4 * 64 * 8 * 2;    // 216 KB

    if (ws_size >= in_f16_bytes + wf_bytes) {
        unsigned int*   in_t = (unsigned int*)d_ws;
        unsigned short* w_f  = (unsigned short*)((char*)d_ws + in_f16_bytes);
        k_prep<<<dim3(512 + 432 + 2048), dim3(256), 0, stream>>>(
            inp, wgt, in_t, w_f, (float4*)out);
        k_main<<<dim3(4096), dim3(128), 0, stream>>>(
            (const unsigned short*)in_t, w_f, off, out);
    } else {
        k_fallback<<<dim3(NB * 256), dim3(256), 0, stream>>>(inp, wgt, off, out);
    }
}

// Round 11
// 109.711 us; speedup vs baseline: 1.6565x; 1.0930x over previous
//
#include <hip/hip_runtime.h>

typedef __attribute__((ext_vector_type(8))) _Float16 half8;
typedef __attribute__((ext_vector_type(4))) float floatx4;

constexpr int NB  = 2;
constexpr int CC  = 64;
constexpr int DD  = 16;
constexpr int HH  = 32;
constexpr int WW  = 32;
constexpr int KN_ = 27;
constexpr int OC  = 64;
constexpr int DHW = DD * HH * WW;   // 16384
constexpr int TP  = 32;             // positions per block tile

__device__ __forceinline__ unsigned short f2h(float f) {
    _Float16 h = (_Float16)f;
    return *(unsigned short*)&h;
}

// ---------------------------------------------------------------------------
// Prep kernel (merged):
//  blocks [0, 512)   : NCDHW f32 -> NDHWC f16  (64 ch contiguous per voxel)
//  blocks [512, 944) : weight (o,c,k) f32 -> f16 MFMA A-fragment stream
//    wf[(((k*2+cc)*4+ot)*64 + l)*8 + i] = W[o=ot*16+(l&15)][c=cc*32+(l>>4)*8+i][k]
__global__ __launch_bounds__(256) void k_prep(const float* __restrict__ in,
                                              const float* __restrict__ w,
                                              unsigned int* __restrict__ outu,
                                              unsigned short* __restrict__ wf) {
    int bid = blockIdx.x;
    int t = threadIdx.x;
    if (bid < 512) {
        __shared__ float tile[64][65];
        int n  = bid >> 8;
        int v0 = (bid & 255) << 6;
        int lane = t & 63, row = t >> 6;
#pragma unroll
        for (int i = 0; i < 16; ++i) {
            int c = (i << 2) + row;
            tile[c][lane] = in[(size_t)(n * CC + c) * DHW + v0 + lane];
        }
        __syncthreads();
#pragma unroll
        for (int i = 0; i < 8; ++i) {
            int flat = i * 256 + t;
            int v = flat >> 5, cd = flat & 31;
            unsigned int lo = f2h(tile[2 * cd][v]);
            unsigned int hi = f2h(tile[2 * cd + 1][v]);
            outu[(size_t)(n * DHW + v0 + v) * 32 + cd] = lo | (hi << 16);
        }
    } else {
        int f = (bid - 512) * 256 + t;   // 110592 total
        int i  = f & 7;
        int l  = (f >> 3) & 63;
        int ot = (f >> 9) & 3;
        int cc = (f >> 11) & 1;
        int k  = f >> 12;
        int o = ot * 16 + (l & 15);
        int c = cc * 32 + ((l >> 4) << 3) + i;
        wf[f] = f2h(w[(o * CC + c) * KN_ + k]);
    }
}

// ---------------------------------------------------------------------------
// TP=32 lockstep deformable conv (r5 core, widened tile).
// 1024 blocks x 256 threads (4 waves) = exactly 4 blocks/CU.
// Block = 32 positions, all 27 taps, all 64 outputs.
// Sampling: sp=t>>3 (32 pos), cg=t&7 (8ch chunk); setup records in LDS.
// MFMA: wave w owns o-tile w (o = w*16..+16) for BOTH p-subtiles ->
//       W frags loaded once per (tap, cc) per wave (2 x 16B/tap, halves W traffic).
__global__ __launch_bounds__(256, 4) void k_main(const unsigned short* __restrict__ inp,
                                                 const unsigned short* __restrict__ wf,
                                                 const float* __restrict__ offs,
                                                 float* __restrict__ out) {
    __shared__ unsigned short S[2 * TP * 64];   // 8KB dbuf [buf][p32][c64] f16, chunk-XOR swz
    __shared__ uint4 SUV[KN_ * TP];             // 864 recs: 8 x u16 voxel ids      (13.8KB)
    __shared__ uint4 SUW[KN_ * TP];             // 864 recs: 8 x f16 corner weights (13.8KB)

    int t   = threadIdx.x;
    int bid = blockIdx.x;
    int n   = (bid >> 2) & 1;                   // XCDs 0-3 -> n=0, 4-7 -> n=1 (L2 locality)
    int idx = ((bid >> 3) << 2) | (bid & 3);    // 0..511
    int p0  = idx << 5;

    int sp = t >> 3;            // 0..31 position in tile
    int cg = t & 7;             // channel chunk (16B of 128B voxel row)
    int w  = t >> 6;            // wave id == o-tile
    int l  = t & 63;
    int lrow = l & 15, lk = l >> 4;

    const float* offb = offs + (size_t)n * (3 * KN_) * DHW + p0;
    const char*  inb  = (const char*)(inp + ((size_t)n * DHW << 6));

    floatx4 acc0 = {0.f, 0.f, 0.f, 0.f};   // p-subtile 0 (p0 + lrow)
    floatx4 acc1 = {0.f, 0.f, 0.f, 0.f};   // p-subtile 1 (p0 + 16 + lrow)

    const int cgo  = cg << 4;
    const int woff = sp * 64 + ((cg ^ (sp & 7)) << 3);             // ushort units
    const int r0   = lrow;
    const int r1   = 16 + lrow;
    const int roff00 = r0 * 64 + (((0 | lk) ^ (r0 & 7)) << 3);     // pt0, cc0
    const int roff01 = r0 * 64 + (((4 | lk) ^ (r0 & 7)) << 3);     // pt0, cc1
    const int roff10 = r1 * 64 + (((0 | lk) ^ (r1 & 7)) << 3);     // pt1, cc0
    const int roff11 = r1 * 64 + (((4 | lk) ^ (r1 & 7)) << 3);     // pt1, cc1

    // ---- setup: 864 (k,p) sampling records, coordinate math once each ----
    for (int si = t; si < KN_ * TP; si += 256) {
        int k = si >> 5, p = si & 31;
        int pa = p0 + p;
        int dpos = pa >> 10, hpos = (pa >> 5) & 31, wpos = pa & 31;

        float oz = offb[(k * 3 + 0) * DHW + p];
        float oy = offb[(k * 3 + 1) * DHW + p];
        float ox = offb[(k * 3 + 2) * DHW + p];
        float ix = ((float)wpos + ox) * (32.0f / 31.0f) - 0.5f;
        float iy = ((float)hpos + oy) * (32.0f / 31.0f) - 0.5f;
        float iz = ((float)dpos + oz) * (16.0f / 15.0f) - 0.5f;
        float xf = floorf(ix), yf = floorf(iy), zf = floorf(iz);
        float fx = ix - xf, fy = iy - yf, fz = iz - zf;
        int x0 = (int)xf, y0 = (int)yf, z0 = (int)zf;

        float wx0 = ((unsigned)x0       < (unsigned)WW) ? 1.f - fx : 0.f;
        float wx1 = ((unsigned)(x0 + 1) < (unsigned)WW) ? fx       : 0.f;
        float wy0 = ((unsigned)y0       < (unsigned)HH) ? 1.f - fy : 0.f;
        float wy1 = ((unsigned)(y0 + 1) < (unsigned)HH) ? fy       : 0.f;
        float wz0 = ((unsigned)z0       < (unsigned)DD) ? 1.f - fz : 0.f;
        float wz1 = ((unsigned)(z0 + 1) < (unsigned)DD) ? fz       : 0.f;

        int xc0 = min(max(x0, 0), WW - 1), xc1 = min(max(x0 + 1, 0), WW - 1);
        int yc0 = min(max(y0, 0), HH - 1), yc1 = min(max(y0 + 1, 0), HH - 1);
        int zc0 = min(max(z0, 0), DD - 1), zc1 = min(max(z0 + 1, 0), DD - 1);

        float wzy00 = wz0 * wy0, wzy01 = wz0 * wy1, wzy10 = wz1 * wy0, wzy11 = wz1 * wy1;
        unsigned int b00 = (zc0 * HH + yc0) * WW, b01 = (zc0 * HH + yc1) * WW;
        unsigned int b10 = (zc1 * HH + yc0) * WW, b11 = (zc1 * HH + yc1) * WW;

        uint4 vp, wp;
        vp.x = (b00 + xc0) | ((b00 + xc1) << 16);
        vp.y = (b01 + xc0) | ((b01 + xc1) << 16);
        vp.z = (b10 + xc0) | ((b10 + xc1) << 16);
        vp.w = (b11 + xc0) | ((b11 + xc1) << 16);
        wp.x = (unsigned int)f2h(wzy00 * wx0) | ((unsigned int)f2h(wzy00 * wx1) << 16);
        wp.y = (unsigned int)f2h(wzy01 * wx0) | ((unsigned int)f2h(wzy01 * wx1) << 16);
        wp.z = (unsigned int)f2h(wzy10 * wx0) | ((unsigned int)f2h(wzy10 * wx1) << 16);
        wp.w = (unsigned int)f2h(wzy11 * wx0) | ((unsigned int)f2h(wzy11 * wx1) << 16);

        SUV[si] = vp;
        SUW[si] = wp;
    }
    __syncthreads();

    // ---- lockstep per-tap loop ----
    for (int k = 0; k < KN_; ++k) {
        // W fragments: wave w needs only (cc=0,ot=w) and (cc=1,ot=w) -> 2 x 16B
        const half8 wa0 = *(const half8*)(wf + (((((k << 1) | 0) << 2) + w) << 9) + (l << 3));
        const half8 wa1 = *(const half8*)(wf + (((((k << 1) | 1) << 2) + w) << 9) + (l << 3));

        // setup record (8 lanes of a position-group broadcast-read 32B)
        const uint4 vp = SUV[(k << 5) + sp];
        const uint4 wp = SUW[(k << 5) + sp];
        const unsigned int vpa[4] = {vp.x, vp.y, vp.z, vp.w};
        const unsigned int wpa[4] = {wp.x, wp.y, wp.z, wp.w};

        half8 accv = {0, 0, 0, 0, 0, 0, 0, 0};
#pragma unroll
        for (int cr = 0; cr < 8; ++cr) {
            unsigned int vd = vpa[cr >> 1];
            unsigned int voxb = ((cr & 1) ? (vd >> 16) : (vd & 0xffffu)) << 7;
            unsigned int wd = wpa[cr >> 1];
            unsigned short wu = (cr & 1) ? (unsigned short)(wd >> 16) : (unsigned short)wd;
            _Float16 wh = *(_Float16*)&wu;
            const half8 v = *(const half8*)(inb + voxb + cgo);
            half8 w8 = {wh, wh, wh, wh, wh, wh, wh, wh};
            accv += v * w8;                      // 4x v_pk_fma_f16
        }
        *(half8*)(S + ((k & 1) << 11) + woff) = accv;

        __syncthreads();

        // MFMA: D[o16 x p16] x 2 p-subtiles, two c-chunks of 32 each
        const unsigned short* Sb = S + ((k & 1) << 11);
        const half8 bf00 = *(const half8*)(Sb + roff00);
        const half8 bf01 = *(const half8*)(Sb + roff01);
        const half8 bf10 = *(const half8*)(Sb + roff10);
        const half8 bf11 = *(const half8*)(Sb + roff11);
        acc0 = __builtin_amdgcn_mfma_f32_16x16x32_f16(wa0, bf00, acc0, 0, 0, 0);
        acc0 = __builtin_amdgcn_mfma_f32_16x16x32_f16(wa1, bf01, acc0, 0, 0, 0);
        acc1 = __builtin_amdgcn_mfma_f32_16x16x32_f16(wa0, bf10, acc1, 0, 0, 0);
        acc1 = __builtin_amdgcn_mfma_f32_16x16x32_f16(wa1, bf11, acc1, 0, 0, 0);
        // dbuf S: next iteration's barrier orders reads vs k+2 overwrite
    }

    // ---- epilogue: o = w*16 + lk*4 + r ; p = p0 + pt*16 + lrow ----
    float* ob = out + ((size_t)n * OC + (w << 4) + (lk << 2)) * DHW + p0 + lrow;
#pragma unroll
    for (int r = 0; r < 4; ++r) {
        ob[r * DHW]      = acc0[r];
        ob[r * DHW + 16] = acc1[r];
    }
}

// ---------------------------------------------------------------------------
// Fallback (no workspace): fp32 fused kernel, original layouts.
__global__ __launch_bounds__(256) void k_fallback(const float* __restrict__ inp,
                                                  const float* __restrict__ wt,
                                                  const float* __restrict__ offs,
                                                  float* __restrict__ out) {
    __shared__ float Slds[64][68];
    __shared__ float Wlds[64 * 64];
    int bid = blockIdx.x;
    int n = bid >> 8;
    int p0 = (bid & 255) * 64;
    int t = threadIdx.x;
    int cq = t & 15, c0 = cq << 2, pslot = t >> 4;
    int ob = (t & 15) << 2, pb = (t >> 4) << 2;
    int swz_w = (((cq & 7) ^ (cq >> 3)) << 2);
    float acc[4][4] = {};
    const float* offbase = offs + (size_t)n * (KN_ * 3) * DHW;
    for (int k = 0; k < KN_; ++k) {
#pragma unroll
        for (int i = 0; i < 16; ++i) {
            int f = i * 256 + t;
            int o = f & 63, c = f >> 6;
            Wlds[f] = wt[(o * CC + c) * KN_ + k];
        }
#pragma unroll
        for (int j = 0; j < 4; ++j) {
            int pl = pslot + 16 * j;
            int pa = p0 + pl;
            int d = pa >> 10, h = (pa >> 5) & 31, w = pa & 31;
            float offz = offbase[(k * 3 + 0) * DHW + pa];
            float offy = offbase[(k * 3 + 1) * DHW + pa];
            float offx = offbase[(k * 3 + 2) * DHW + pa];
            float ix = ((float)w + offx) * (32.0f / 31.0f) - 0.5f;
            float iy = ((float)h + offy) * (32.0f / 31.0f) - 0.5f;
            float iz = ((float)d + offz) * (16.0f / 15.0f) - 0.5f;
            float xf = floorf(ix), yf = floorf(iy), zf = floorf(iz);
            float fx = ix - xf, fy = iy - yf, fz = iz - zf;
            int x0 = (int)xf, y0 = (int)yf, z0 = (int)zf;
            float wx0 = 1.0f - fx, wx1 = fx, wy0 = 1.0f - fy, wy1 = fy, wz0 = 1.0f - fz, wz1 = fz;
            float s0 = 0.f, s1 = 0.f, s2 = 0.f, s3 = 0.f;
#pragma unroll
            for (int dz = 0; dz < 2; ++dz) {
                int zc = z0 + dz;
                if ((unsigned)zc >= (unsigned)DD) continue;
                float wz = dz ? wz1 : wz0;
#pragma unroll
                for (int dy = 0; dy < 2; ++dy) {
                    int yc = y0 + dy;
                    if ((unsigned)yc >= (unsigned)HH) continue;
                    float wzy = wz * (dy ? wy1 : wy0);
#pragma unroll
                    for (int dx = 0; dx < 2; ++dx) {
                        int xc = x0 + dx;
                        if ((unsigned)xc >= (unsigned)WW) continue;
                        float wf = wzy * (dx ? wx1 : wx0);
                        int vox = (zc * HH + yc) * WW + xc;
                        const float* b = inp + (size_t)(n * CC + c0) * DHW + vox;
                        s0 += wf * b[0]; s1 += wf * b[DHW];
                        s2 += wf * b[2 * DHW]; s3 += wf * b[3 * DHW];
                    }
                }
            }
            int plw = pl ^ swz_w;
            Slds[c0 + 0][plw] = s0; Slds[c0 + 1][plw] = s1;
            Slds[c0 + 2][plw] = s2; Slds[c0 + 3][plw] = s3;
        }
        __syncthreads();
#pragma unroll
        for (int c = 0; c < 64; ++c) {
            const int g = ((c >> 2) & 7) ^ (c >> 5);
            float4 wv = *(const float4*)(Wlds + c * 64 + ob);
            float4 sv = *(const float4*)(&Slds[c][pb ^ (g << 2)]);
            float wa[4] = {wv.x, wv.y, wv.z, wv.w};
            float sa[4] = {sv.x, sv.y, sv.z, sv.w};
#pragma unroll
            for (int i = 0; i < 4; ++i)
#pragma unroll
                for (int jj = 0; jj < 4; ++jj) acc[i][jj] += wa[i] * sa[jj];
        }
        __syncthreads();
    }
#pragma unroll
    for (int i = 0; i < 4; ++i) {
        float4 vv;
        vv.x = acc[i][0]; vv.y = acc[i][1]; vv.z = acc[i][2]; vv.w = acc[i][3];
        *(float4*)(out + (size_t)(n * OC + ob + i) * DHW + p0 + pb) = vv;
    }
}

// ---------------------------------------------------------------------------
extern "C" void kernel_launch(void* const* d_in, const int* in_sizes, int n_in,
                              void* d_out, int out_size, void* d_ws, size_t ws_size,
                              hipStream_t stream) {
    const float* inp = (const float*)d_in[0];
    const float* off = (const float*)d_in[1];
    const float* wgt = (const float*)d_in[2];
    float* out = (float*)d_out;

    const size_t in_f16_bytes = (size_t)NB * DHW * CC * 2;           // 4 MB
    const size_t wf_bytes     = (size_t)KN_ * 2 * 4 * 64 * 8 * 2;    // 216 KB

    if (ws_size >= in_f16_bytes + wf_bytes) {
        unsigned int*   in_t = (unsigned int*)d_ws;
        unsigned short* w_f  = (unsigned short*)((char*)d_ws + in_f16_bytes);
        k_prep<<<dim3(512 + 432), dim3(256), 0, stream>>>(inp, wgt, in_t, w_f);
        k_main<<<dim3(1024), dim3(256), 0, stream>>>(
            (const unsigned short*)in_t, w_f, off, out);
    } else {
        k_fallback<<<dim3(NB * 256), dim3(256), 0, stream>>>(inp, wgt, off, out);
    }
}